// Round 6
// baseline (715.471 us; speedup 1.0000x reference)
//
#include <hip/hip_runtime.h>
#include <math.h>

#define HIDDEN 16
#define CIN 5
#define BB 8
#define TT 12
#define HH 256
#define WW 256
// legacy (per-step fallback) tile geometry
#define TX 32
#define TY 8
#define HALO_X 34
#define HALO_Y 10
#define NPX (HALO_X * HALO_Y)
#define STRIDE 40
// persistent tile geometry: 32x4, 4 visits per block
#define PTX 32
#define PTY 4
#define PHX 34
#define PHY 6
#define PNPX (PHX * PHY)        // 204 staged pixels
#define ROWSH 24                // shorts per staged px: h[16] | x[8] (48 B)
#define NTILES 4096
#define NBLK_PERSIST 1024       // 4 blocks/CU x 256 CU, 4 tiles each
#define XSTEP (HH * WW * 8)     // xp shorts per t-slice per batch
// compressed W table: [tap][gate][lane48][8] + 8-short zero pad (quad3 = 0)
#define WSH (9 * 4 * 48 * 8)    // 13824 shorts
#define WSH_PAD (WSH + 8)       // + zero block
// persistent LDS layout (shorts)
#define TILE_SH (PNPX * ROWSH)  // 4896
#define WOFF TILE_SH
#define ZOFF (TILE_SH + WSH)    // zero block (filled from table pad)
#define SMSH (TILE_SH + WSH_PAD) // 18728 shorts = 37456 B <= 40 KB

typedef __attribute__((ext_vector_type(8))) short bf16x8;   // 8 bf16 (4 VGPRs)
typedef __attribute__((ext_vector_type(4))) float floatx4;

__device__ __forceinline__ unsigned short f2bf(float f) {   // RNE fp32->bf16
    unsigned int u = __float_as_uint(f);
    u += 0x7fffu + ((u >> 16) & 1u);
    return (unsigned short)(u >> 16);
}
__device__ __forceinline__ float bf2f(unsigned short s) {
    return __uint_as_float(((unsigned int)s) << 16);
}
__device__ __forceinline__ float rcpf(float x) {            // v_rcp_f32 (~1 ulp)
    float r;
    asm("v_rcp_f32 %0, %1" : "=v"(r) : "v"(x));
    return r;
}
__device__ __forceinline__ float fast_sigmoid(float x) {
    return rcpf(1.0f + __expf(-x));
}
__device__ __forceinline__ float fast_tanh(float x) {
    float e2 = __expf(-2.0f * fabsf(x));
    float t = (1.0f - e2) * rcpf(1.0f + e2);
    return copysignf(t, x);
}
// legacy-path gates (div-based, proven)
__device__ __forceinline__ float leg_sigmoid(float x) { return 1.0f / (1.0f + __expf(-x)); }
__device__ __forceinline__ float leg_tanh(float x) {
    float e2 = __expf(-2.0f * fabsf(x));
    float t = (1.0f - e2) / (1.0f + e2);
    return copysignf(t, x);
}

// Pack W_cell [64][21][3][3] into COMPRESSED B-fragment layout for
// mfma_f32_16x16x32_bf16: Wfrag[tap][gate][lane48][j] (quad3 is all-zero and
// stored once as an 8-short pad at the end). lane holds
// B[k=(lane>>4)*8+j][col=lane&15], col = hidden unit, N-tile = gate.
// k-order: 0..15 = h units (ci_ref 5+k), 16..20 = x chans, 21..23 = 0.
__global__ void prep_w_kernel(const float* __restrict__ Wc,
                              unsigned short* __restrict__ Wfrag) {
    int i = blockIdx.x * 256 + threadIdx.x;
    if (i >= WSH_PAD) return;
    if (i >= WSH) { Wfrag[i] = 0; return; }   // shared zero block (quad3)
    int j    = i & 7;
    int t8   = i >> 3;
    int lane = t8 % 48;
    int t48  = t8 / 48;
    int g    = t48 & 3;
    int tap  = t48 >> 2;
    int k    = ((lane >> 4) << 3) + j;        // 0..23
    int col  = lane & 15;
    int o    = g * 16 + col;
    float w  = 0.0f;
    if (k < 21) {
        int ci_ref = (k < 16) ? (5 + k) : (k - 16);
        w = Wc[(o * 21 + ci_ref) * 9 + tap];
    }
    Wfrag[i] = f2bf(w);
}

// One-time x repack: planar fp32 [b][t][c][y][x] -> channel-last bf16 [b][t][y][x][8]
__global__ void prep_x_kernel(const float* __restrict__ x,
                              unsigned short* __restrict__ xp) {
    size_t n = (size_t)blockIdx.x * 256 + threadIdx.x;
    const size_t TOTPX = (size_t)BB * TT * HH * WW;
    if (n >= TOTPX) return;
    size_t bt  = n / (size_t)(HH * WW);
    size_t pix = n - bt * (size_t)(HH * WW);
    const float* src = x + bt * (size_t)CIN * HH * WW + pix;
    unsigned short v[8];
    #pragma unroll
    for (int c = 0; c < CIN; ++c) v[c] = f2bf(src[(size_t)c * HH * WW]);
    v[5] = 0; v[6] = 0; v[7] = 0;
    *(uint4*)&xp[n * 8] = *(const uint4*)v;
}

__global__ void prep_flags_kernel(unsigned int* __restrict__ flags) {
    int i = blockIdx.x * 256 + threadIdx.x;
    if (i < NTILES) flags[i] = 0;
}

// ---------------------------------------------------------------------------
// Persistent kernel: W-fragments resident in LDS (zero L2 weight traffic).
// 1024 blocks (4/CU), each owns 4 tiles of 32x4 (one 128x4 strip, same row).
// Per visit: stage 204-px halo (h from global, x from xp) -> barrier ->
// 9-tap MFMA loop reading A from LDS tile and B from LDS W-table ->
// gates + register c update -> h to global -> publish tile flag.
// Tile n = bid*4 + v; batch = bid>>7; ty = (bid>>1)&63; tx = n&7.
// ---------------------------------------------------------------------------
__global__ __launch_bounds__(256, 4)
void convlstm_persistent_kernel(const float* __restrict__ x,
                                const unsigned short* __restrict__ xp,  // may be null
                                unsigned short* __restrict__ ha,
                                unsigned short* __restrict__ hbuf,
                                const unsigned short* __restrict__ Wfrag,
                                const float* __restrict__ bias,
                                const float* __restrict__ Wf,
                                const float* __restrict__ bfin,
                                float* __restrict__ out,
                                unsigned int* __restrict__ flags,
                                int use_xp) {
    __shared__ unsigned short sm[SMSH];   // tile | W-table | zero block

    const int tid  = threadIdx.x;
    const int lane = tid & 63;
    const int wave = tid >> 6;
    const int u    = lane & 15;
    const int quad = lane >> 4;
    const int bid  = (int)blockIdx.x;

    const int bb = bid >> 7;              // batch
    const int ty = (bid >> 1) & 63;
    const int y0 = ty * PTY;
    const int n0 = bid * 4;               // first tile id

    // ---- one-time: W table -> LDS (includes the zero pad at ZOFF) ----
    for (int i = tid; i < WSH_PAD / 8; i += 256)
        *(uint4*)&sm[WOFF + i * 8] = *(const uint4*)&Wfrag[i * 8];

    // per-lane W read base: lanes 48-63 -> shared zero block (broadcast)
    const int wbl   = (lane < 48) ? (WOFF + lane * 8) : ZOFF;
    const int wstep = (lane < 48) ? 384 : 0;   // shorts per (tap,gate)

    // ---- neighbor poll descriptors (wave0 lanes 0..7) ----
    int nb_dy = 0, nb_dx = 0;
    {
        int s  = lane + (lane >= 4 ? 1 : 0);   // skip center
        nb_dy = s / 3 - 1;
        nb_dx = s - (s / 3) * 3 - 1;
    }

    // ---- staging descriptors (tid < 204), visit-invariant parts ----
    const int sly = tid / PHX;
    const int slx = tid - sly * PHX;
    const int gy  = y0 + sly - 1;
    const bool yok = (gy >= 0) && (gy < HH);
    const int hbase_y = (bb * HH * WW + gy * WW) * HIDDEN;        // + gx*16
    const int xbase_y = (bb * TT * HH * WW + gy * WW) * 8;        // + t*XSTEP + gx*8

    float bg[4];
    #pragma unroll
    for (int g = 0; g < 4; ++g) bg[g] = bias[g * 16 + u];
    const float wfu = Wf[u];
    const float bf0 = bfin[0];

    // A-fragment addressing (visit-invariant): wave = output row
    int A[2];
    #pragma unroll
    for (int mh = 0; mh < 2; ++mh)
        A[mh] = (quad < 3) ? ((wave * PHX + mh * 16 + u) * ROWSH + quad * 8)
                           : ZOFF;
    const int msel = (quad < 3) ? ROWSH : 0;

    // c-state: 4 visits x [mh][r]; named arrays + 2-bit static-pattern select
    float cV0[2][4], cV1[2][4], cV2[2][4], cV3[2][4];
    #pragma unroll
    for (int m = 0; m < 2; ++m)
        #pragma unroll
        for (int r = 0; r < 4; ++r) {
            cV0[m][r] = 0.0f; cV1[m][r] = 0.0f;
            cV2[m][r] = 0.0f; cV3[m][r] = 0.0f;
        }

    #pragma unroll 1
    for (int t = 0; t < TT; ++t) {
        const unsigned short* h_in  = (t & 1) ? ha : hbuf;
        unsigned short*       h_out = (t & 1) ? hbuf : ha;
        const int first = (t == 0);
        const int last  = (t == TT - 1);

        #pragma unroll 1
        for (int v = 0; v < 4; ++v) {
            const int n  = n0 + v;
            const int tx = n & 7;
            const int x0 = tx * PTX;

            // ---- (A) wait for 8 neighbor tiles at step t-1 ----
            if (t > 0) {
                if (wave == 0) {
                    bool act = (lane < 8) && (tx + nb_dx >= 0) && (tx + nb_dx < 8)
                                          && (ty + nb_dy >= 0) && (ty + nb_dy < 64);
                    int nb = n + nb_dy * 8 + nb_dx;
                    const unsigned need = (unsigned)t;
                    for (;;) {
                        unsigned fv = act
                            ? __hip_atomic_load(&flags[nb], __ATOMIC_RELAXED,
                                                __HIP_MEMORY_SCOPE_AGENT)
                            : 0xFFFFFFFFu;
                        if (__all(fv >= need)) break;
                        __builtin_amdgcn_s_sleep(2);
                    }
                    if (tid == 0) __threadfence();   // acquire
                }
                __syncthreads();
            }

            // ---- (B) stage halo: h from global, x from xp ----
            if (tid < PNPX) {
                unsigned short* row = &sm[tid * ROWSH];
                uint4 z = {0, 0, 0, 0};
                int gx = x0 + slx - 1;
                bool inb = yok && ((unsigned)gx < (unsigned)WW);
                if (inb && !first) {
                    const unsigned short* hp = h_in + hbase_y + gx * HIDDEN;
                    *(uint4*)&row[0] = *(const uint4*)&hp[0];
                    *(uint4*)&row[8] = *(const uint4*)&hp[8];
                } else {
                    *(uint4*)&row[0] = z;
                    *(uint4*)&row[8] = z;
                }
                if (use_xp) {
                    if (inb)
                        *(uint4*)&row[16] =
                            *(const uint4*)&xp[xbase_y + t * XSTEP + gx * 8];
                    else
                        *(uint4*)&row[16] = z;
                } else {
                    unsigned short vv[8];
                    #pragma unroll
                    for (int ci = 0; ci < CIN; ++ci) {
                        float f = 0.0f;
                        if (inb) f = x[(((size_t)bb * TT + t) * CIN + ci)
                                       * (size_t)(HH * WW) + gy * WW + gx];
                        vv[ci] = f2bf(f);
                    }
                    vv[5] = 0; vv[6] = 0; vv[7] = 0;
                    *(uint4*)&row[16] = *(const uint4*)vv;
                }
            }
            __syncthreads();   // stage done (also covers W fill at t=0,v=0)

            // ---- (C) compute: wave = row, mh = col half; acc[2][4] ----
            floatx4 acc[2][4];
            #pragma unroll
            for (int mh = 0; mh < 2; ++mh)
                #pragma unroll
                for (int g = 0; g < 4; ++g)
                    acc[mh][g] = (floatx4){bg[g], bg[g], bg[g], bg[g]};

            #pragma unroll 3
            for (int tap = 0; tap < 9; ++tap) {
                int ky = tap / 3;
                int kx = tap - ky * 3;
                int ktap = ky * PHX + kx;
                bf16x8 bfr[4];
                #pragma unroll
                for (int g = 0; g < 4; ++g)
                    bfr[g] = *(const bf16x8*)&sm[wbl + (tap * 4 + g) * wstep];
                #pragma unroll
                for (int mh = 0; mh < 2; ++mh) {
                    bf16x8 af = *(const bf16x8*)&sm[A[mh] + ktap * msel];
                    #pragma unroll
                    for (int g = 0; g < 4; ++g)
                        acc[mh][g] = __builtin_amdgcn_mfma_f32_16x16x32_bf16(
                            af, bfr[g], acc[mh][g], 0, 0, 0);
                }
            }

            // ---- (D) epilogue: gates + register c + h/out stores ----
            #pragma unroll
            for (int mh = 0; mh < 2; ++mh) {
                int py = y0 + wave;
                int col0 = mh * 16 + quad * 4;
                size_t gidx0 = ((size_t)bb * HH * WW + (size_t)py * WW + x0 + col0)
                               * HIDDEN + u;
                #pragma unroll
                for (int r = 0; r < 4; ++r) {
                    float ig = fast_sigmoid(acc[mh][0][r]);
                    float fg = fast_sigmoid(acc[mh][1][r]);
                    float og = fast_sigmoid(acc[mh][2][r]);
                    float gg = fast_tanh(acc[mh][3][r]);
                    float c_old = (v & 2) ? ((v & 1) ? cV3[mh][r] : cV2[mh][r])
                                          : ((v & 1) ? cV1[mh][r] : cV0[mh][r]);
                    float c_new = fg * c_old + ig * gg;
                    if (v & 2) { if (v & 1) cV3[mh][r] = c_new; else cV2[mh][r] = c_new; }
                    else       { if (v & 1) cV1[mh][r] = c_new; else cV0[mh][r] = c_new; }
                    float hval = og * fast_tanh(c_new);
                    if (last) {
                        // fused 1x1 conv: sum over 16 channels (u lanes of quad)
                        float s = wfu * hval;
                        s += __shfl_xor(s, 1);
                        s += __shfl_xor(s, 2);
                        s += __shfl_xor(s, 4);
                        s += __shfl_xor(s, 8);
                        if (u == 0)
                            out[(size_t)bb * HH * WW + (size_t)py * WW + x0 + col0 + r]
                                = s + bf0;
                    } else {
                        h_out[gidx0 + (size_t)r * HIDDEN] = f2bf(hval);
                    }
                }
            }

            // ---- (E) end-of-visit barrier + publish ----
            __syncthreads();   // LDS reads done (next stage may overwrite);
                               // also drains each wave's vmcnt before barrier
            if (!last && tid == 0) {
                __threadfence();   // release h stores
                __hip_atomic_store(&flags[n], (unsigned)(t + 1), __ATOMIC_RELAXED,
                                   __HIP_MEMORY_SCOPE_AGENT);
            }
        }
    }
}

// ---------------------------------------------------------------------------
// Legacy per-step path (round-0 structure, compressed W table) — fallback.
// ---------------------------------------------------------------------------
__global__ __launch_bounds__(256, 5)
void convlstm_step_kernel(const float* __restrict__ x, int t,
                          const unsigned short* __restrict__ xp,  // may be null
                          const unsigned short* __restrict__ h_in,
                          unsigned short* __restrict__ h_out,
                          float* __restrict__ c_state,
                          const unsigned short* __restrict__ Wfrag,
                          const float* __restrict__ bias,
                          int first, int use_xp) {
    __shared__ unsigned short tile[NPX * STRIDE];   // 27200 B

    const int tid  = threadIdx.x;
    const int lane = tid & 63;
    const int wave = tid >> 6;
    const int x0 = blockIdx.x * TX;
    const int y0 = blockIdx.y * TY;
    const int bb = blockIdx.z;

    for (int i = tid; i < NPX; i += 256) {
        int ly = i / HALO_X;
        int lx = i - ly * HALO_X;
        int gy = y0 + ly - 1;
        int gx = x0 + lx - 1;
        bool inb = (gy >= 0 && gy < HH && gx >= 0 && gx < WW);
        unsigned short* row = &tile[i * STRIDE];
        uint4 z = {0, 0, 0, 0};
        if (inb && !first) {
            size_t hbase = ((size_t)bb * HH * WW + (size_t)gy * WW + gx) * HIDDEN;
            *(uint4*)&row[0] = *(const uint4*)&h_in[hbase];
            *(uint4*)&row[8] = *(const uint4*)&h_in[hbase + 8];
        } else {
            *(uint4*)&row[0] = z;
            *(uint4*)&row[8] = z;
        }
        if (use_xp) {
            if (inb) {
                size_t xb = (((size_t)bb * TT + t) * (size_t)(HH * WW)
                             + (size_t)gy * WW + gx) * 8;
                *(uint4*)&row[16] = *(const uint4*)&xp[xb];
            } else {
                *(uint4*)&row[16] = z;
            }
        } else {
            #pragma unroll
            for (int ci = 0; ci < CIN; ++ci) {
                float v = 0.0f;
                if (inb) v = x[(((size_t)bb * TT + t) * CIN + ci) * (size_t)(HH * WW)
                               + (size_t)gy * WW + gx];
                row[16 + ci] = f2bf(v);
            }
            row[21] = 0; row[22] = 0; row[23] = 0;
        }
        *(uint4*)&row[24] = z;
    }
    __syncthreads();

    const int u    = lane & 15;
    const int quad = lane >> 4;

    const unsigned short* wptr = (lane < 48) ? (Wfrag + lane * 8) : (Wfrag + WSH);
    const int wstep2 = (lane < 48) ? 384 : 0;

    float bg[4];
    #pragma unroll
    for (int g = 0; g < 4; ++g) bg[g] = bias[g * 16 + u];

    #pragma unroll 1
    for (int half = 0; half < 2; ++half) {
        floatx4 acc[2][4];
        int abase[2];
        #pragma unroll
        for (int mh = 0; mh < 2; ++mh) {
            int ml = half * 2 + mh;
            int m  = wave + ml * 4;
            int my = m >> 1;
            int mx = (m & 1) << 4;
            abase[mh] = (my * HALO_X + mx + u) * STRIDE + quad * 8;
            #pragma unroll
            for (int g = 0; g < 4; ++g)
                acc[mh][g] = (floatx4){bg[g], bg[g], bg[g], bg[g]};
        }

        #pragma unroll 3
        for (int tap = 0; tap < 9; ++tap) {
            int ky = tap / 3;
            int kx = tap - ky * 3;
            int toff = (ky * HALO_X + kx) * STRIDE;
            bf16x8 bfr[4];
            #pragma unroll
            for (int g = 0; g < 4; ++g)
                bfr[g] = *(const bf16x8*)&wptr[(tap * 4 + g) * wstep2];
            #pragma unroll
            for (int mh = 0; mh < 2; ++mh) {
                bf16x8 af = *(const bf16x8*)&tile[abase[mh] + toff];
                #pragma unroll
                for (int g = 0; g < 4; ++g)
                    acc[mh][g] = __builtin_amdgcn_mfma_f32_16x16x32_bf16(
                        af, bfr[g], acc[mh][g], 0, 0, 0);
            }
        }

        #pragma unroll
        for (int mh = 0; mh < 2; ++mh) {
            int ml = half * 2 + mh;
            int m  = wave + ml * 4;
            int my = m >> 1;
            int mx = (m & 1) << 4;
            int py = y0 + my;
            #pragma unroll
            for (int r = 0; r < 4; ++r) {
                int pxx = x0 + mx + quad * 4 + r;
                size_t idx = ((size_t)bb * HH * WW + (size_t)py * WW + pxx) * HIDDEN + u;
                float ig = leg_sigmoid(acc[mh][0][r]);
                float fg = leg_sigmoid(acc[mh][1][r]);
                float og = leg_sigmoid(acc[mh][2][r]);
                float gg = leg_tanh(acc[mh][3][r]);
                float c_old = first ? 0.0f : c_state[idx];
                float c_new = fg * c_old + ig * gg;
                c_state[idx] = c_new;
                h_out[idx] = f2bf(og * leg_tanh(c_new));
            }
        }
    }
}

// Final 1x1 conv from bf16 channel-last h (legacy path only)
__global__ void final_conv_kernel(const unsigned short* __restrict__ h,
                                  const float* __restrict__ Wf,
                                  const float* __restrict__ bf_,
                                  float* __restrict__ out) {
    int i = blockIdx.x * 256 + threadIdx.x;
    if (i >= BB * HH * WW) return;
    size_t base = (size_t)i * HIDDEN;
    uint4 v0 = *(const uint4*)&h[base];
    uint4 v1 = *(const uint4*)&h[base + 8];
    const unsigned short* p0 = (const unsigned short*)&v0;
    const unsigned short* p1 = (const unsigned short*)&v1;
    float s = bf_[0];
    #pragma unroll
    for (int k = 0; k < 8; ++k) s += Wf[k] * bf2f(p0[k]);
    #pragma unroll
    for (int k = 0; k < 8; ++k) s += Wf[8 + k] * bf2f(p1[k]);
    out[i] = s;
}

extern "C" void kernel_launch(void* const* d_in, const int* in_sizes, int n_in,
                              void* d_out, int out_size, void* d_ws, size_t ws_size,
                              hipStream_t stream) {
    const float* x  = (const float*)d_in[0];
    const float* Wc = (const float*)d_in[1];
    const float* bc = (const float*)d_in[2];
    const float* Wf = (const float*)d_in[3];
    const float* bf = (const float*)d_in[4];
    float* out = (float*)d_out;

    char* ws = (char*)d_ws;
    const size_t h_bytes = (size_t)BB * HH * WW * HIDDEN * 2;   // 16.78 MB
    const size_t c_bytes = (size_t)BB * HH * WW * HIDDEN * 4;   // 33.55 MB
    const size_t w_bytes = (size_t)WSH_PAD * 2;                 // 27.7 KB
    const size_t f_bytes = (size_t)NTILES * 4;                  // 16 KB flags
    const size_t x_bytes = (size_t)BB * TT * HH * WW * 8 * 2;   // 100.7 MB

    unsigned short* h_a = (unsigned short*)(ws);
    unsigned short* h_b = (unsigned short*)(ws + h_bytes);
    float* c            = (float*)(ws + 2 * h_bytes);
    unsigned short* Wfr = (unsigned short*)(ws + 2 * h_bytes + c_bytes);
    unsigned int* flags = (unsigned int*)(ws + 2 * h_bytes + c_bytes + w_bytes);
    unsigned short* xp  = (unsigned short*)(ws + 2 * h_bytes + c_bytes + w_bytes + f_bytes);

    const int use_xp =
        (ws_size >= 2 * h_bytes + c_bytes + w_bytes + f_bytes + x_bytes) ? 1 : 0;

    prep_w_kernel<<<(WSH_PAD + 255) / 256, 256, 0, stream>>>(Wc, Wfr);
    prep_flags_kernel<<<(NTILES + 255) / 256, 256, 0, stream>>>(flags);
    if (use_xp) {
        size_t totpx = (size_t)BB * TT * HH * WW;
        prep_x_kernel<<<(int)((totpx + 255) / 256), 256, 0, stream>>>(x, xp);
    }

    // Preferred path: persistent kernel with W-in-LDS.
    int occ = 0;
    hipOccupancyMaxActiveBlocksPerMultiprocessor(&occ, convlstm_persistent_kernel,
                                                 256, 0);
    bool done = false;
    if (occ >= 4) {
        const unsigned short* xp_arg = use_xp ? xp : (const unsigned short*)0;
        int use_xp_arg = use_xp;
        void* kargs[] = {
            (void*)&x, (void*)&xp_arg, (void*)&h_a, (void*)&h_b,
            (void*)&Wfr, (void*)&bc, (void*)&Wf, (void*)&bf,
            (void*)&out, (void*)&flags, (void*)&use_xp_arg
        };
        if (hipLaunchCooperativeKernel((const void*)convlstm_persistent_kernel,
                                       dim3(NBLK_PERSIST, 1, 1), dim3(256, 1, 1),
                                       kargs, 0, stream) == hipSuccess)
            done = true;
    }

    if (!done) {
        // Legacy per-step path (round-0 behavior)
        dim3 grid(WW / TX, HH / TY, BB);   // 2048 blocks
        dim3 block(256, 1, 1);
        const unsigned short* h_in = h_a;
        for (int t = 0; t < TT; ++t) {
            unsigned short* h_out = (t & 1) ? h_b : h_a;
            convlstm_step_kernel<<<grid, block, 0, stream>>>(
                x, t, use_xp ? xp : (const unsigned short*)0,
                h_in, h_out, c, Wfr, bc, (t == 0) ? 1 : 0, use_xp);
            h_in = h_out;
        }
        final_conv_kernel<<<(BB * HH * WW + 255) / 256, 256, 0, stream>>>(
            h_in, Wf, bf, out);
    }
}

// Round 7
// 713.482 us; speedup vs baseline: 1.0028x; 1.0028x over previous
//
#include <hip/hip_runtime.h>
#include <math.h>

#define HIDDEN 16
#define CIN 5
#define BB 8
#define TT 12
#define HH 256
#define WW 256
// legacy (per-step fallback) tile geometry
#define TX 32
#define TY 8
#define HALO_X 34
#define HALO_Y 10
#define NPX (HALO_X * HALO_Y)
#define STRIDE 40
// persistent tile geometry: 64x8, 2 visits per block, 512 threads
#define PTX 64
#define PTY 8
#define PHX 66
#define PHY 10
#define PNPX (PHX * PHY)        // 660 staged pixels
#define ROWSH 28                // shorts per staged px: h[16]|x[8]|pad[4] (56 B)
                                // bank stride 14, gcd(14,32)=2 -> 2-way (free)
#define NTILES 1024
#define NBLK_PERSIST 512        // 2 blocks/CU x 256 CU, 2 tiles each
#define NTHR 512                // 8 waves
#define XSTEP (HH * WW * 8)     // xp shorts per t-slice per batch
// compressed W table: [tap][gate][lane48][8] + 8-short zero pad (quad3 = 0)
#define WSH (9 * 4 * 48 * 8)    // 13824 shorts
#define WSH_PAD (WSH + 8)
// persistent LDS layout (shorts)
#define TILE_SH (PNPX * ROWSH)  // 18480
#define WOFF TILE_SH
#define ZOFF (TILE_SH + WSH)    // zero block (the W pad)
#define SMSH (TILE_SH + WSH_PAD)   // 32312 shorts = 64624 B (2 blocks/CU ok)

typedef __attribute__((ext_vector_type(8))) short bf16x8;   // 8 bf16 (4 VGPRs)
typedef __attribute__((ext_vector_type(4))) float floatx4;

__device__ __forceinline__ unsigned short f2bf(float f) {   // RNE fp32->bf16
    unsigned int u = __float_as_uint(f);
    u += 0x7fffu + ((u >> 16) & 1u);
    return (unsigned short)(u >> 16);
}
__device__ __forceinline__ float bf2f(unsigned short s) {
    return __uint_as_float(((unsigned int)s) << 16);
}
__device__ __forceinline__ float rcpf(float x) {            // v_rcp_f32 (~1 ulp)
    float r;
    asm("v_rcp_f32 %0, %1" : "=v"(r) : "v"(x));
    return r;
}
__device__ __forceinline__ float fast_sigmoid(float x) {
    return rcpf(1.0f + __expf(-x));
}
__device__ __forceinline__ float fast_tanh(float x) {
    float e2 = __expf(-2.0f * fabsf(x));
    float t = (1.0f - e2) * rcpf(1.0f + e2);
    return copysignf(t, x);
}
// legacy-path gates (div-based, proven)
__device__ __forceinline__ float leg_sigmoid(float x) { return 1.0f / (1.0f + __expf(-x)); }
__device__ __forceinline__ float leg_tanh(float x) {
    float e2 = __expf(-2.0f * fabsf(x));
    float t = (1.0f - e2) / (1.0f + e2);
    return copysignf(t, x);
}

// Pack W_cell [64][21][3][3] into COMPRESSED B-fragment layout for
// mfma_f32_16x16x32_bf16: Wfrag[tap][gate][lane48][j] (quad3 all-zero, stored
// once as an 8-short pad at the end). lane holds B[k=(lane>>4)*8+j][col],
// col = lane&15 = hidden unit, N-tile = gate.
// k-order: 0..15 = h units (ci_ref 5+k), 16..20 = x chans, 21..23 = 0.
__global__ void prep_w_kernel(const float* __restrict__ Wc,
                              unsigned short* __restrict__ Wfrag) {
    int i = blockIdx.x * 256 + threadIdx.x;
    if (i >= WSH_PAD) return;
    if (i >= WSH) { Wfrag[i] = 0; return; }   // shared zero block (quad3)
    int j    = i & 7;
    int t8   = i >> 3;
    int lane = t8 % 48;
    int t48  = t8 / 48;
    int g    = t48 & 3;
    int tap  = t48 >> 2;
    int k    = ((lane >> 4) << 3) + j;        // 0..23
    int col  = lane & 15;
    int o    = g * 16 + col;
    float w  = 0.0f;
    if (k < 21) {
        int ci_ref = (k < 16) ? (5 + k) : (k - 16);
        w = Wc[(o * 21 + ci_ref) * 9 + tap];
    }
    Wfrag[i] = f2bf(w);
}

// One-time x repack: planar fp32 [b][t][c][y][x] -> channel-last bf16 [b][t][y][x][8]
__global__ void prep_x_kernel(const float* __restrict__ x,
                              unsigned short* __restrict__ xp) {
    size_t n = (size_t)blockIdx.x * 256 + threadIdx.x;
    const size_t TOTPX = (size_t)BB * TT * HH * WW;
    if (n >= TOTPX) return;
    size_t bt  = n / (size_t)(HH * WW);
    size_t pix = n - bt * (size_t)(HH * WW);
    const float* src = x + bt * (size_t)CIN * HH * WW + pix;
    unsigned short v[8];
    #pragma unroll
    for (int c = 0; c < CIN; ++c) v[c] = f2bf(src[(size_t)c * HH * WW]);
    v[5] = 0; v[6] = 0; v[7] = 0;
    *(uint4*)&xp[n * 8] = *(const uint4*)v;
}

__global__ void prep_flags_kernel(unsigned int* __restrict__ flags) {
    int i = blockIdx.x * 256 + threadIdx.x;
    if (i < NTILES) flags[i] = 0;
}

// ---------------------------------------------------------------------------
// Persistent kernel: W-fragments resident in LDS, 512 threads (8 waves),
// 2 blocks/CU, each block owns 2 horizontally-adjacent 64x8 tiles.
// Per visit: stage 660-px halo (h+x) -> barrier -> 9-tap MFMA loop with
// A (pixels) and B (weights) both from LDS -> gates + register c ->
// h to global -> publish flag. Tile n = bid*2 + v; bb,ty constant per block.
// ---------------------------------------------------------------------------
__global__ __launch_bounds__(NTHR, 4)
void convlstm_persistent_kernel(const float* __restrict__ x,
                                const unsigned short* __restrict__ xp,  // may be null
                                unsigned short* __restrict__ ha,
                                unsigned short* __restrict__ hbuf,
                                const unsigned short* __restrict__ Wfrag,
                                const float* __restrict__ bias,
                                const float* __restrict__ Wf,
                                const float* __restrict__ bfin,
                                float* __restrict__ out,
                                unsigned int* __restrict__ flags,
                                int use_xp) {
    __shared__ unsigned short sm[SMSH];   // tile | W-table | zero pad

    const int tid  = threadIdx.x;
    const int lane = tid & 63;
    const int wave = tid >> 6;            // 0..7
    const int u    = lane & 15;
    const int quad = lane >> 4;
    const int bid  = (int)blockIdx.x;

    // tiles n0, n0+1: same batch/row, adjacent columns
    const int n0  = bid * 2;
    const int bb  = n0 >> 7;
    const int q0  = n0 & 127;
    const int ty  = q0 >> 2;
    const int tx0 = q0 & 3;
    const int y0  = ty * PTY;

    // ---- one-time: W table -> LDS (includes the zero pad) ----
    for (int i = tid; i < WSH_PAD / 8; i += NTHR)
        *(uint4*)&sm[WOFF + i * 8] = *(const uint4*)&Wfrag[i * 8];

    // per-lane W read base (lanes 48-63 -> shared zero block, broadcast)
    const int wbl   = (lane < 48) ? (WOFF + lane * 8) : ZOFF;
    const int wstep = (lane < 48) ? 384 : 0;   // shorts per (tap,gate)

    // ---- neighbor poll deltas (wave0 lanes 0..7) ----
    int nb_dy = 0, nb_dx = 0;
    {
        int s  = lane + (lane >= 4 ? 1 : 0);   // skip center
        nb_dy = s / 3 - 1;
        nb_dx = s - (s / 3) * 3 - 1;
    }

    // ---- staging descriptors: rows tid and tid+512 (tid<PNPX-512) ----
    const int sly0 = tid / PHX;
    const int slx0 = tid - sly0 * PHX;
    const int i1   = tid + NTHR;
    const int sly1 = i1 / PHX;
    const int slx1 = i1 - sly1 * PHX;
    const int gy0  = y0 + sly0 - 1;
    const int gy1  = y0 + sly1 - 1;
    const bool yok0 = (gy0 >= 0) && (gy0 < HH);
    const bool yok1 = (gy1 >= 0) && (gy1 < HH);
    const int hb0 = (bb * HH * WW + gy0 * WW) * HIDDEN;
    const int hb1 = (bb * HH * WW + gy1 * WW) * HIDDEN;
    const int xb0 = (bb * TT * HH * WW + gy0 * WW) * 8;
    const int xb1 = (bb * TT * HH * WW + gy1 * WW) * 8;

    float bg[4];
    #pragma unroll
    for (int g = 0; g < 4; ++g) bg[g] = bias[g * 16 + u];
    const float wfu = Wf[u];
    const float bf0 = bfin[0];
    const int msel  = (quad < 3) ? ROWSH : 0;
    const int mx    = (wave & 3) * 16;         // column band
    const int rbase = (wave >> 2) * 4;         // row group: 0..3 or 4..7

    // c-state: [visit v][quarter qq] -> 4 named arrays [mh][r], ternary select
    float cA0[2][4], cA1[2][4], cB0[2][4], cB1[2][4];
    #pragma unroll
    for (int m = 0; m < 2; ++m)
        #pragma unroll
        for (int r = 0; r < 4; ++r) {
            cA0[m][r] = 0.0f; cA1[m][r] = 0.0f;
            cB0[m][r] = 0.0f; cB1[m][r] = 0.0f;
        }

    #pragma unroll 1
    for (int t = 0; t < TT; ++t) {
        const unsigned short* h_in  = (t & 1) ? ha : hbuf;
        unsigned short*       h_out = (t & 1) ? hbuf : ha;
        const int first = (t == 0);
        const int last  = (t == TT - 1);

        #pragma unroll 1
        for (int v = 0; v < 2; ++v) {
            const int n  = n0 + v;
            const int tx = tx0 + v;
            const int x0 = tx * PTX;

            // ---- (A) wait for 8 neighbor tiles at step t-1 ----
            if (t > 0) {
                if (wave == 0) {
                    bool act = (lane < 8) && (tx + nb_dx >= 0) && (tx + nb_dx < 4)
                                          && (ty + nb_dy >= 0) && (ty + nb_dy < 32);
                    int nb = n + nb_dy * 4 + nb_dx;
                    const unsigned need = (unsigned)t;
                    for (;;) {
                        unsigned fv = act
                            ? __hip_atomic_load(&flags[nb], __ATOMIC_RELAXED,
                                                __HIP_MEMORY_SCOPE_AGENT)
                            : 0xFFFFFFFFu;
                        if (__all(fv >= need)) break;
                        __builtin_amdgcn_s_sleep(2);
                    }
                    if (tid == 0) __threadfence();   // acquire
                }
                __syncthreads();
            }

            // ---- (B) stage halo: h + x (both rounds) ----
            {
                unsigned short* row = &sm[tid * ROWSH];
                uint4 z = {0, 0, 0, 0};
                int gx = x0 + slx0 - 1;
                bool inb = yok0 && ((unsigned)gx < (unsigned)WW);
                if (inb && !first) {
                    const unsigned short* hp = h_in + hb0 + gx * HIDDEN;
                    *(uint4*)&row[0] = *(const uint4*)&hp[0];
                    *(uint4*)&row[8] = *(const uint4*)&hp[8];
                } else {
                    *(uint4*)&row[0] = z; *(uint4*)&row[8] = z;
                }
                if (use_xp) {
                    if (inb)
                        *(uint4*)&row[16] = *(const uint4*)&xp[xb0 + t * XSTEP + gx * 8];
                    else
                        *(uint4*)&row[16] = z;
                } else {
                    unsigned short vv[8];
                    #pragma unroll
                    for (int ci = 0; ci < CIN; ++ci) {
                        float f = 0.0f;
                        if (inb) f = x[(((size_t)bb * TT + t) * CIN + ci)
                                       * (size_t)(HH * WW) + gy0 * WW + gx];
                        vv[ci] = f2bf(f);
                    }
                    vv[5] = 0; vv[6] = 0; vv[7] = 0;
                    *(uint4*)&row[16] = *(const uint4*)vv;
                }
            }
            if (tid < PNPX - NTHR) {
                unsigned short* row = &sm[i1 * ROWSH];
                uint4 z = {0, 0, 0, 0};
                int gx = x0 + slx1 - 1;
                bool inb = yok1 && ((unsigned)gx < (unsigned)WW);
                if (inb && !first) {
                    const unsigned short* hp = h_in + hb1 + gx * HIDDEN;
                    *(uint4*)&row[0] = *(const uint4*)&hp[0];
                    *(uint4*)&row[8] = *(const uint4*)&hp[8];
                } else {
                    *(uint4*)&row[0] = z; *(uint4*)&row[8] = z;
                }
                if (use_xp) {
                    if (inb)
                        *(uint4*)&row[16] = *(const uint4*)&xp[xb1 + t * XSTEP + gx * 8];
                    else
                        *(uint4*)&row[16] = z;
                } else {
                    unsigned short vv[8];
                    #pragma unroll
                    for (int ci = 0; ci < CIN; ++ci) {
                        float f = 0.0f;
                        if (inb) f = x[(((size_t)bb * TT + t) * CIN + ci)
                                       * (size_t)(HH * WW) + gy1 * WW + gx];
                        vv[ci] = f2bf(f);
                    }
                    vv[5] = 0; vv[6] = 0; vv[7] = 0;
                    *(uint4*)&row[16] = *(const uint4*)vv;
                }
            }
            __syncthreads();   // stage done (covers W fill at t=0,v=0)

            // ---- (C)+(D) compute 2 quarters: rows rbase+qq*2+{0,1} ----
            #pragma unroll 1
            for (int qq = 0; qq < 2; ++qq) {
                floatx4 acc[2][4];
                int A[2];
                #pragma unroll
                for (int mh = 0; mh < 2; ++mh) {
                    int my = rbase + qq * 2 + mh;
                    A[mh] = (quad < 3)
                        ? ((my * PHX + mx + u) * ROWSH + quad * 8) : ZOFF;
                    #pragma unroll
                    for (int g = 0; g < 4; ++g)
                        acc[mh][g] = (floatx4){bg[g], bg[g], bg[g], bg[g]};
                }

                #pragma unroll 3
                for (int tap = 0; tap < 9; ++tap) {
                    int ky = tap / 3;
                    int kx = tap - ky * 3;
                    int ktap = ky * PHX + kx;
                    bf16x8 bfr[4];
                    #pragma unroll
                    for (int g = 0; g < 4; ++g)
                        bfr[g] = *(const bf16x8*)&sm[wbl + (tap * 4 + g) * wstep];
                    #pragma unroll
                    for (int mh = 0; mh < 2; ++mh) {
                        bf16x8 af = *(const bf16x8*)&sm[A[mh] + ktap * msel];
                        #pragma unroll
                        for (int g = 0; g < 4; ++g)
                            acc[mh][g] = __builtin_amdgcn_mfma_f32_16x16x32_bf16(
                                af, bfr[g], acc[mh][g], 0, 0, 0);
                    }
                }

                // ---- epilogue: gates + register c + stores ----
                #pragma unroll
                for (int mh = 0; mh < 2; ++mh) {
                    int my = rbase + qq * 2 + mh;
                    int py = y0 + my;
                    int col0 = mx + quad * 4;
                    size_t gidx0 = ((size_t)bb * HH * WW + (size_t)py * WW + x0 + col0)
                                   * HIDDEN + u;
                    #pragma unroll
                    for (int r = 0; r < 4; ++r) {
                        float ig = fast_sigmoid(acc[mh][0][r]);
                        float fg = fast_sigmoid(acc[mh][1][r]);
                        float og = fast_sigmoid(acc[mh][2][r]);
                        float gg = fast_tanh(acc[mh][3][r]);
                        float c_old = v ? (qq ? cB1[mh][r] : cB0[mh][r])
                                        : (qq ? cA1[mh][r] : cA0[mh][r]);
                        float c_new = fg * c_old + ig * gg;
                        if (v) { if (qq) cB1[mh][r] = c_new; else cB0[mh][r] = c_new; }
                        else   { if (qq) cA1[mh][r] = c_new; else cA0[mh][r] = c_new; }
                        float hval = og * fast_tanh(c_new);
                        if (last) {
                            // fused 1x1 conv: sum over 16 channels (u lanes)
                            float s = wfu * hval;
                            s += __shfl_xor(s, 1);
                            s += __shfl_xor(s, 2);
                            s += __shfl_xor(s, 4);
                            s += __shfl_xor(s, 8);
                            if (u == 0)
                                out[(size_t)bb * HH * WW + (size_t)py * WW
                                    + x0 + col0 + r] = s + bf0;
                        } else {
                            h_out[gidx0 + (size_t)r * HIDDEN] = f2bf(hval);
                        }
                    }
                }
            }

            // ---- (E) end-of-visit barrier + publish ----
            __syncthreads();   // LDS reads done; drains vmcnt before barrier
            if (!last && tid == 0) {
                __threadfence();   // release h stores
                __hip_atomic_store(&flags[n], (unsigned)(t + 1), __ATOMIC_RELAXED,
                                   __HIP_MEMORY_SCOPE_AGENT);
            }
        }
    }
}

// ---------------------------------------------------------------------------
// Legacy per-step path (round-0 structure, compressed W table) — fallback.
// ---------------------------------------------------------------------------
__global__ __launch_bounds__(256, 5)
void convlstm_step_kernel(const float* __restrict__ x, int t,
                          const unsigned short* __restrict__ xp,  // may be null
                          const unsigned short* __restrict__ h_in,
                          unsigned short* __restrict__ h_out,
                          float* __restrict__ c_state,
                          const unsigned short* __restrict__ Wfrag,
                          const float* __restrict__ bias,
                          int first, int use_xp) {
    __shared__ unsigned short tile[NPX * STRIDE];   // 27200 B

    const int tid  = threadIdx.x;
    const int lane = tid & 63;
    const int wave = tid >> 6;
    const int x0 = blockIdx.x * TX;
    const int y0 = blockIdx.y * TY;
    const int bb = blockIdx.z;

    for (int i = tid; i < NPX; i += 256) {
        int ly = i / HALO_X;
        int lx = i - ly * HALO_X;
        int gy = y0 + ly - 1;
        int gx = x0 + lx - 1;
        bool inb = (gy >= 0 && gy < HH && gx >= 0 && gx < WW);
        unsigned short* row = &tile[i * STRIDE];
        uint4 z = {0, 0, 0, 0};
        if (inb && !first) {
            size_t hbase = ((size_t)bb * HH * WW + (size_t)gy * WW + gx) * HIDDEN;
            *(uint4*)&row[0] = *(const uint4*)&h_in[hbase];
            *(uint4*)&row[8] = *(const uint4*)&h_in[hbase + 8];
        } else {
            *(uint4*)&row[0] = z;
            *(uint4*)&row[8] = z;
        }
        if (use_xp) {
            if (inb) {
                size_t xb = (((size_t)bb * TT + t) * (size_t)(HH * WW)
                             + (size_t)gy * WW + gx) * 8;
                *(uint4*)&row[16] = *(const uint4*)&xp[xb];
            } else {
                *(uint4*)&row[16] = z;
            }
        } else {
            #pragma unroll
            for (int ci = 0; ci < CIN; ++ci) {
                float v = 0.0f;
                if (inb) v = x[(((size_t)bb * TT + t) * CIN + ci) * (size_t)(HH * WW)
                               + (size_t)gy * WW + gx];
                row[16 + ci] = f2bf(v);
            }
            row[21] = 0; row[22] = 0; row[23] = 0;
        }
        *(uint4*)&row[24] = z;
    }
    __syncthreads();

    const int u    = lane & 15;
    const int quad = lane >> 4;

    const unsigned short* wptr = (lane < 48) ? (Wfrag + lane * 8) : (Wfrag + WSH);
    const int wstep2 = (lane < 48) ? 384 : 0;

    float bg[4];
    #pragma unroll
    for (int g = 0; g < 4; ++g) bg[g] = bias[g * 16 + u];

    #pragma unroll 1
    for (int half = 0; half < 2; ++half) {
        floatx4 acc[2][4];
        int abase[2];
        #pragma unroll
        for (int mh = 0; mh < 2; ++mh) {
            int ml = half * 2 + mh;
            int m  = wave + ml * 4;
            int my = m >> 1;
            int mx = (m & 1) << 4;
            abase[mh] = (my * HALO_X + mx + u) * STRIDE + quad * 8;
            #pragma unroll
            for (int g = 0; g < 4; ++g)
                acc[mh][g] = (floatx4){bg[g], bg[g], bg[g], bg[g]};
        }

        #pragma unroll 3
        for (int tap = 0; tap < 9; ++tap) {
            int ky = tap / 3;
            int kx = tap - ky * 3;
            int toff = (ky * HALO_X + kx) * STRIDE;
            bf16x8 bfr[4];
            #pragma unroll
            for (int g = 0; g < 4; ++g)
                bfr[g] = *(const bf16x8*)&wptr[(tap * 4 + g) * wstep2];
            #pragma unroll
            for (int mh = 0; mh < 2; ++mh) {
                bf16x8 af = *(const bf16x8*)&tile[abase[mh] + toff];
                #pragma unroll
                for (int g = 0; g < 4; ++g)
                    acc[mh][g] = __builtin_amdgcn_mfma_f32_16x16x32_bf16(
                        af, bfr[g], acc[mh][g], 0, 0, 0);
            }
        }

        #pragma unroll
        for (int mh = 0; mh < 2; ++mh) {
            int ml = half * 2 + mh;
            int m  = wave + ml * 4;
            int my = m >> 1;
            int mx = (m & 1) << 4;
            int py = y0 + my;
            #pragma unroll
            for (int r = 0; r < 4; ++r) {
                int pxx = x0 + mx + quad * 4 + r;
                size_t idx = ((size_t)bb * HH * WW + (size_t)py * WW + pxx) * HIDDEN + u;
                float ig = leg_sigmoid(acc[mh][0][r]);
                float fg = leg_sigmoid(acc[mh][1][r]);
                float og = leg_sigmoid(acc[mh][2][r]);
                float gg = leg_tanh(acc[mh][3][r]);
                float c_old = first ? 0.0f : c_state[idx];
                float c_new = fg * c_old + ig * gg;
                c_state[idx] = c_new;
                h_out[idx] = f2bf(og * leg_tanh(c_new));
            }
        }
    }
}

// Final 1x1 conv from bf16 channel-last h (legacy path only)
__global__ void final_conv_kernel(const unsigned short* __restrict__ h,
                                  const float* __restrict__ Wf,
                                  const float* __restrict__ bf_,
                                  float* __restrict__ out) {
    int i = blockIdx.x * 256 + threadIdx.x;
    if (i >= BB * HH * WW) return;
    size_t base = (size_t)i * HIDDEN;
    uint4 v0 = *(const uint4*)&h[base];
    uint4 v1 = *(const uint4*)&h[base + 8];
    const unsigned short* p0 = (const unsigned short*)&v0;
    const unsigned short* p1 = (const unsigned short*)&v1;
    float s = bf_[0];
    #pragma unroll
    for (int k = 0; k < 8; ++k) s += Wf[k] * bf2f(p0[k]);
    #pragma unroll
    for (int k = 0; k < 8; ++k) s += Wf[8 + k] * bf2f(p1[k]);
    out[i] = s;
}

extern "C" void kernel_launch(void* const* d_in, const int* in_sizes, int n_in,
                              void* d_out, int out_size, void* d_ws, size_t ws_size,
                              hipStream_t stream) {
    const float* x  = (const float*)d_in[0];
    const float* Wc = (const float*)d_in[1];
    const float* bc = (const float*)d_in[2];
    const float* Wf = (const float*)d_in[3];
    const float* bf = (const float*)d_in[4];
    float* out = (float*)d_out;

    char* ws = (char*)d_ws;
    const size_t h_bytes = (size_t)BB * HH * WW * HIDDEN * 2;   // 16.78 MB
    const size_t c_bytes = (size_t)BB * HH * WW * HIDDEN * 4;   // 33.55 MB
    const size_t w_bytes = (size_t)WSH_PAD * 2;                 // 27.7 KB
    const size_t f_bytes = (size_t)NTILES * 4;                  // 4 KB flags
    const size_t x_bytes = (size_t)BB * TT * HH * WW * 8 * 2;   // 100.7 MB

    unsigned short* h_a = (unsigned short*)(ws);
    unsigned short* h_b = (unsigned short*)(ws + h_bytes);
    float* c            = (float*)(ws + 2 * h_bytes);
    unsigned short* Wfr = (unsigned short*)(ws + 2 * h_bytes + c_bytes);
    unsigned int* flags = (unsigned int*)(ws + 2 * h_bytes + c_bytes + w_bytes);
    unsigned short* xp  = (unsigned short*)(ws + 2 * h_bytes + c_bytes + w_bytes + f_bytes);

    const int use_xp =
        (ws_size >= 2 * h_bytes + c_bytes + w_bytes + f_bytes + x_bytes) ? 1 : 0;

    prep_w_kernel<<<(WSH_PAD + 255) / 256, 256, 0, stream>>>(Wc, Wfr);
    prep_flags_kernel<<<(NTILES + 255) / 256, 256, 0, stream>>>(flags);
    if (use_xp) {
        size_t totpx = (size_t)BB * TT * HH * WW;
        prep_x_kernel<<<(int)((totpx + 255) / 256), 256, 0, stream>>>(x, xp);
    }

    // Preferred path: persistent kernel, W-in-LDS, 512x512 geometry.
    int occ = 0;
    hipOccupancyMaxActiveBlocksPerMultiprocessor(&occ, convlstm_persistent_kernel,
                                                 NTHR, 0);
    bool done = false;
    if (occ >= 2) {
        const unsigned short* xp_arg = use_xp ? xp : (const unsigned short*)0;
        int use_xp_arg = use_xp;
        void* kargs[] = {
            (void*)&x, (void*)&xp_arg, (void*)&h_a, (void*)&h_b,
            (void*)&Wfr, (void*)&bc, (void*)&Wf, (void*)&bf,
            (void*)&out, (void*)&flags, (void*)&use_xp_arg
        };
        if (hipLaunchCooperativeKernel((const void*)convlstm_persistent_kernel,
                                       dim3(NBLK_PERSIST, 1, 1), dim3(NTHR, 1, 1),
                                       kargs, 0, stream) == hipSuccess)
            done = true;
    }

    if (!done) {
        // Legacy per-step path (round-0 behavior, compressed W)
        dim3 grid(WW / TX, HH / TY, BB);   // 2048 blocks
        dim3 block(256, 1, 1);
        const unsigned short* h_in = h_a;
        for (int t = 0; t < TT; ++t) {
            unsigned short* h_out = (t & 1) ? h_b : h_a;
            convlstm_step_kernel<<<grid, block, 0, stream>>>(
                x, t, use_xp ? xp : (const unsigned short*)0,
                h_in, h_out, c, Wfr, bc, (t == 0) ? 1 : 0, use_xp);
            h_in = h_out;
        }
        final_conv_kernel<<<(BB * HH * WW + 255) / 256, 256, 0, stream>>>(
            h_in, Wf, bf, out);
    }
}